// Round 6
// baseline (57.677 us; speedup 1.0000x reference)
//
#include <hip/hip_runtime.h>

#define PAD 10
#define CS 128
#define CSP 148           // CS + 2*PAD
#define AH 4000
#define AW 4000
#define RPT 4             // output rows per thread
#define BROWS (2*RPT)     // rows per block

typedef float v2f __attribute__((ext_vector_type(2)));

__device__ __forceinline__ v2f pk_fma(v2f a, v2f b, v2f c) {
    return __builtin_elementwise_fma(a, b, c);
}

// ---- general-path PREP (R5, unchanged) ----
#define PREPG(S, IXF, IYF)                                                    \
    do {                                                                      \
        const float fx0_ = floorf(IXF), fy0_ = floorf(IYF);                   \
        txs[S] = (IXF) - fx0_; tys[S] = (IYF) - fy0_;                         \
        const int ixi_ = (int)fx0_, iyi_ = (int)fy0_;                         \
        ixis[S] = ixi_; iyis[S] = iyi_;                                       \
        fasts[S] = (ixi_ - 1 >= lo_c) & (ixi_ + 2 <= hi_c) &                  \
                   (iyi_ - 1 >= lo_r) & (iyi_ + 2 <= hi_r);                   \
        int mr_ = gr0 + iyi_ - 1; mr_ = mr_ < 0 ? 0 : (mr_ > AH-4 ? AH-4 : mr_); \
        int mc_ = gc0 + ixi_ - 1; mc_ = mc_ < 0 ? 0 : (mc_ > AW-4 ? AW-4 : mc_); \
        const float* p_ = matrix + (size_t)mr_ * AW + mc_;                    \
        __builtin_memcpy(&qg[S][0], p_,        16);                           \
        __builtin_memcpy(&qg[S][1], p_ + AW,   16);                           \
        __builtin_memcpy(&qg[S][2], p_ + 2*AW, 16);                           \
        __builtin_memcpy(&qg[S][3], p_ + 3*AW, 16);                           \
    } while (0)

// ---- lean-path PREP: coords + frac + 4 unclamped loads ----
#define PREPF(S, KF)                                                          \
    do {                                                                      \
        const float ixf_ = fmaf((KF), t01, ixf0);                             \
        const float iyf_ = fmaf((KF), t11, iyf0);                             \
        const float fx_ = floorf(ixf_), fy_ = floorf(iyf_);                   \
        tp[S] = (v2f){ixf_ - fx_, iyf_ - fy_};                                \
        const int off_ = base_el + ((int)fy_ - 1)*AW + ((int)fx_ - 1);        \
        const float* p_ = matrix + off_;                                      \
        __builtin_memcpy(&q[S][0], p_,        16);                            \
        __builtin_memcpy(&q[S][1], p_ + AW,   16);                            \
        __builtin_memcpy(&q[S][2], p_ + 2*AW, 16);                            \
        __builtin_memcpy(&q[S][3], p_ + 3*AW, 16);                            \
    } while (0)

__global__ __launch_bounds__(256) void shift_bicubic_kernel(
    const float* __restrict__ matrix,
    const float* __restrict__ theta,
    float* __restrict__ out)
{
    const int n   = blockIdx.x;          // tile index 0..1023
    const int i0  = n >> 5;
    const int i1  = n & 31;
    const int c   = threadIdx.x & 127;
    const int sub = threadIdx.x >> 7;
    const int rb  = blockIdx.y * BROWS;              // block's first row
    const int r0  = rb + sub*RPT;
    const int w   = i1 * CS + c;
    const int h0  = i0 * CS + r0;
    if (w >= AW || h0 >= AH) return;

    const float t00 = theta[n*6+0], t01 = theta[n*6+1], t02 = theta[n*6+2];
    const float t10 = theta[n*6+3], t11 = theta[n*6+4], t12 = theta[n*6+5];

    const float xs  = (2.0f*(float)(c + PAD) + 1.0f) * (1.0f/148.0f) - 1.0f;
    const float ys0 = (2.0f*(float)(r0 + PAD) + 1.0f) * (1.0f/148.0f) - 1.0f;
    const float bx  = fmaf(t00, xs, t02);
    const float by  = fmaf(t10, xs, t12);
    // sample coords advance by exactly t01/t11 per output row
    const float ixf0 = fmaf(fmaf(t01, ys0, bx), 74.0f, 73.5f);
    const float iyf0 = fmaf(fmaf(t11, ys0, by), 74.0f, 73.5f);

    const int gr0 = i0*CS - 2*PAD;
    const int gc0 = i1*CS - 2*PAD;
    const int lo_c = (gc0 < 0) ? -gc0 : 0;
    const int hi_c = (gc0 + CSP - 1 > AW - 1) ? (AW - 1 - gc0) : (CSP - 1);
    const int lo_r = (gr0 < 0) ? -gr0 : 0;
    const int hi_r = (gr0 + CSP - 1 > AH - 1) ? (AH - 1 - gr0) : (CSP - 1);

    // ---- block-uniform all-fast corner test (ix/iy affine in (c,r)) ----
    const int cact = (AW - 1 - i1*CS < CS - 1) ? (AW - 1 - i1*CS) : (CS - 1);
    const int ract = (rb + BROWS - 1 < AH - 1 - i0*CS) ? (rb + BROWS - 1)
                                                       : (AH - 1 - i0*CS);
    const float xsA = (2.0f*(float)(PAD)        + 1.0f)*(1.0f/148.0f) - 1.0f;
    const float xsB = (2.0f*(float)(cact + PAD) + 1.0f)*(1.0f/148.0f) - 1.0f;
    const float ysA = (2.0f*(float)(rb   + PAD) + 1.0f)*(1.0f/148.0f) - 1.0f;
    const float ysB = (2.0f*(float)(ract + PAD) + 1.0f)*(1.0f/148.0f) - 1.0f;
    const float ixAA = fmaf(fmaf(t01, ysA, fmaf(t00, xsA, t02)), 74.0f, 73.5f);
    const float ixAB = fmaf(fmaf(t01, ysB, fmaf(t00, xsA, t02)), 74.0f, 73.5f);
    const float ixBA = fmaf(fmaf(t01, ysA, fmaf(t00, xsB, t02)), 74.0f, 73.5f);
    const float ixBB = fmaf(fmaf(t01, ysB, fmaf(t00, xsB, t02)), 74.0f, 73.5f);
    const float iyAA = fmaf(fmaf(t11, ysA, fmaf(t10, xsA, t12)), 74.0f, 73.5f);
    const float iyAB = fmaf(fmaf(t11, ysB, fmaf(t10, xsA, t12)), 74.0f, 73.5f);
    const float iyBA = fmaf(fmaf(t11, ysA, fmaf(t10, xsB, t12)), 74.0f, 73.5f);
    const float iyBB = fmaf(fmaf(t11, ysB, fmaf(t10, xsB, t12)), 74.0f, 73.5f);
    const float ixmn = fminf(fminf(ixAA, ixAB), fminf(ixBA, ixBB));
    const float ixmx = fmaxf(fmaxf(ixAA, ixAB), fmaxf(ixBA, ixBB));
    const float iymn = fminf(fminf(iyAA, iyAB), fminf(iyBA, iyBB));
    const float iymx = fmaxf(fmaxf(iyAA, iyAB), fmaxf(iyBA, iyBB));
    const bool allfast =
        (ixmn >= (float)(lo_c + 1) + 0.01f) & (ixmx <= (float)(hi_c - 1) - 0.01f) &
        (iymn >= (float)(lo_r + 1) + 0.01f) & (iymx <= (float)(hi_r - 1) - 0.01f);

    int oidx = h0*AW + w;

    if (allfast) {
        // allfast blocks never touch matrix OOB; base_el >= 0 here
        const int base_el = gr0*AW + gc0;
        v2f    tp[2];
        float4 q[2][4];
        PREPF(0, 0.0f);
        #pragma unroll
        for (int k = 0; k < RPT; ++k) {
            if (k + 1 < RPT) PREPF((k+1)&1, (float)(k+1));
            __builtin_amdgcn_sched_barrier(0);
            const int S = k & 1;
            // packed cubic weights: lane .x = x-axis, lane .y = y-axis
            const v2f t  = tp[S];
            const v2f s  = 1.0f - t;
            const v2f t2 = t*t, s2 = s*s;
            const v2f w0 = (-0.75f*t)*s2;
            const v2f w3 = (-0.75f*s)*t2;
            const v2f w1 = pk_fma(t2, pk_fma((v2f)1.25f, t, (v2f)(-2.25f)), (v2f)1.0f);
            const v2f w2 = pk_fma(s2, pk_fma((v2f)1.25f, s, (v2f)(-2.25f)), (v2f)1.0f);
            const float wx0=w0.x, wy0=w0.y, wx1=w1.x, wy1=w1.y;
            const float wx2=w2.x, wy2=w2.y, wx3=w3.x, wy3=w3.y;
            const float4 q0=q[S][0], q1=q[S][1], q2=q[S][2], q3=q[S][3];
            const float a0 = fmaf(wx3,q0.w, fmaf(wx2,q0.z, fmaf(wx1,q0.y, wx0*q0.x)));
            const float a1 = fmaf(wx3,q1.w, fmaf(wx2,q1.z, fmaf(wx1,q1.y, wx0*q1.x)));
            const float a2 = fmaf(wx3,q2.w, fmaf(wx2,q2.z, fmaf(wx1,q2.y, wx0*q2.x)));
            const float a3 = fmaf(wx3,q3.w, fmaf(wx2,q3.z, fmaf(wx1,q3.y, wx0*q3.x)));
            const float acc = fmaf(wy3,a3, fmaf(wy2,a2, fmaf(wy1,a1, wy0*a0)));
            __builtin_nontemporal_store(acc, &out[oidx]);
            oidx += AW;
        }
    } else {
        // general path (R5, verified)
        float  txs[2], tys[2];
        int    ixis[2], iyis[2];
        bool   fasts[2];
        float4 qg[2][4];
        PREPG(0, ixf0, iyf0);
        #pragma unroll
        for (int k = 0; k < RPT; ++k) {
            if (k + 1 < RPT) {
                const float ixfn = fmaf((float)(k+1), t01, ixf0);
                const float iyfn = fmaf((float)(k+1), t11, iyf0);
                PREPG((k+1)&1, ixfn, iyfn);
            }
            __builtin_amdgcn_sched_barrier(0);
            const int   S  = k & 1;
            const float tx = txs[S], ty = tys[S];
            const float A_ = -0.75f, AP2 = 1.25f, mAP3 = -2.25f;
            const float sx = 1.0f - tx, sy = 1.0f - ty;
            const float tx2 = tx*tx, sx2 = sx*sx;
            const float ty2 = ty*ty, sy2 = sy*sy;
            const float wx0 = A_*(tx*sx2);
            const float wx3 = A_*(sx*tx2);
            const float wx1 = fmaf(tx2, fmaf(AP2, tx, mAP3), 1.0f);
            const float wx2 = fmaf(sx2, fmaf(AP2, sx, mAP3), 1.0f);
            const float wy0 = A_*(ty*sy2);
            const float wy3 = A_*(sy*ty2);
            const float wy1 = fmaf(ty2, fmaf(AP2, ty, mAP3), 1.0f);
            const float wy2 = fmaf(sy2, fmaf(AP2, sy, mAP3), 1.0f);

            float acc;
            if (fasts[S]) {
                const float4 q0 = qg[S][0], q1 = qg[S][1], q2 = qg[S][2], q3 = qg[S][3];
                const float a0 = fmaf(wx3,q0.w, fmaf(wx2,q0.z, fmaf(wx1,q0.y, wx0*q0.x)));
                const float a1 = fmaf(wx3,q1.w, fmaf(wx2,q1.z, fmaf(wx1,q1.y, wx0*q1.x)));
                const float a2 = fmaf(wx3,q2.w, fmaf(wx2,q2.z, fmaf(wx1,q2.y, wx0*q2.x)));
                const float a3 = fmaf(wx3,q3.w, fmaf(wx2,q3.z, fmaf(wx1,q3.y, wx0*q3.x)));
                acc = fmaf(wy3,a3, fmaf(wy2,a2, fmaf(wy1,a1, wy0*a0)));
            } else {
                const float wxa[4] = {wx0, wx1, wx2, wx3};
                const float wya[4] = {wy0, wy1, wy2, wy3};
                const int ixi = ixis[S], iyi = iyis[S];
                acc = 0.0f;
                #pragma unroll
                for (int ky = 0; ky < 4; ++ky) {
                    const int row = iyi - 1 + ky;
                    const int gr  = gr0 + row;
                    const bool rok = (row >= 0) & (row < CSP) & (gr >= 0) & (gr < AH);
                    float racc = 0.0f;
                    #pragma unroll
                    for (int kx = 0; kx < 4; ++kx) {
                        const int col = ixi - 1 + kx;
                        const int gc  = gc0 + col;
                        const bool cok = rok & (col >= 0) & (col < CSP) & (gc >= 0) & (gc < AW);
                        const float v = cok ? matrix[(size_t)gr*AW + gc] : 0.0f;
                        racc = fmaf(wxa[kx], v, racc);
                    }
                    acc = fmaf(wya[ky], racc, acc);
                }
            }
            if (h0 + k < AH) __builtin_nontemporal_store(acc, &out[oidx]);
            oidx += AW;
        }
    }
}

extern "C" void kernel_launch(void* const* d_in, const int* in_sizes, int n_in,
                              void* d_out, int out_size, void* d_ws, size_t ws_size,
                              hipStream_t stream) {
    const float* matrix = (const float*)d_in[0];
    const float* theta  = (const float*)d_in[1];
    float* out = (float*)d_out;

    dim3 block(256, 1, 1);
    dim3 grid(1024, CS/BROWS, 1);   // 1024 tiles x 16 row-groups
    shift_bicubic_kernel<<<grid, block, 0, stream>>>(matrix, theta, out);
}